// Round 1
// baseline (287.942 us; speedup 1.0000x reference)
//
#include <hip/hip_runtime.h>

// CorrelationAlign: out[b, a*63+c, i, j] = in[b, (a+i-31)*32 + (c+j-31), i, j]
//   valid iff 0 <= a+i-31 < 32 and 0 <= c+j-31 < 32, else 0.
// b=16, h=w=32, H=W=63.
// Output-driven: writes (260 MB) are coalesced float4; reads (64 MB unique)
// are strided gathers absorbed by L2/L3 (input is only 64 MB, < L3 256 MB).

#define B_DIM   16
#define HW      32
#define HH      63
#define TOTAL4  (B_DIM * HH * HH * HW * HW / 4)   // 16,257,024 float4s

__global__ __launch_bounds__(256) void CorrelationAlign_kernel(
    const float* __restrict__ in, float* __restrict__ out, int total4) {
  const int stride = gridDim.x * blockDim.x;
  for (int idx = blockIdx.x * blockDim.x + threadIdx.x; idx < total4;
       idx += stride) {
    // idx = (((b*3969 + a*63 + c) * 32) + i) * 8 + j4
    const int j4   = idx & 7;
    const int i    = (idx >> 3) & 31;
    const int rem  = idx >> 8;        // b*3969 + a*63 + c
    const int c    = rem % 63;
    const int rem2 = rem / 63;
    const int a    = rem2 % 63;
    const int b    = rem2 / 63;

    const int p = a + i - 31;         // source "row" block index
    float4 v = make_float4(0.f, 0.f, 0.f, 0.f);
    if ((unsigned)p < 32u) {
      // in offset = (b*1024 + p*32 + q)*1024 + i*32 + j
      const float* base = in + ((size_t)(b * 1024 + p * 32) * 1024 + i * 32);
      const int j0 = j4 * 4;
      float* vp = reinterpret_cast<float*>(&v);
#pragma unroll
      for (int t = 0; t < 4; ++t) {
        const int j = j0 + t;
        const int q = c + j - 31;
        if ((unsigned)q < 32u) vp[t] = base[(size_t)q * 1024 + j];
      }
    }
    reinterpret_cast<float4*>(out)[idx] = v;   // coalesced 16B store
  }
}

extern "C" void kernel_launch(void* const* d_in, const int* in_sizes, int n_in,
                              void* d_out, int out_size, void* d_ws,
                              size_t ws_size, hipStream_t stream) {
  const float* in = (const float*)d_in[0];
  float* out = (float*)d_out;
  const int total4 = TOTAL4;
  const int block = 256;
  const int grid = 4096;  // grid-stride; ~31 float4s per thread
  CorrelationAlign_kernel<<<grid, block, 0, stream>>>(in, out, total4);
}

// Round 2
// 58.826 us; speedup vs baseline: 4.8948x; 4.8948x over previous
//
#include <hip/hip_runtime.h>

// CorrelationAlign: out[b, a*63+c, i, j] = in[b, (a+i-31)*32 + (c+j-31), i, j]
//   valid iff 0 <= a+i-31 < 32 and 0 <= c+j-31 < 32, else 0.
// b=16, h=w=32, H=W=63.
//
// LDS diagonal-transpose formulation: one block per (b, a, i).
//   p = a+i-31 fixed per block. Input tile in[b, p*32+q, i, j] (q,j in [0,32)^2)
//   = 32 contiguous 128B rows -> coalesced loads, each input line fetched
//   exactly once chip-wide (no inter-block input sharing). Output = 63 rows
//   (c in [0,63)) of 32 floats, coalesced float4 stores, reading the LDS
//   diagonal q = c+j-31. LDS stride 33: diagonal read addr = c*33 + 34j
//   -> bank delta 2 per lane -> 2-way aliasing (free, m136).
// Blocks with p invalid (31/63 of a-values per i) write pure zeros.

#define HSZ 32
#define HH  63
#define LDSS 33   // padded LDS row stride (floats)

__global__ __launch_bounds__(256) void CorrelationAlign_kernel(
    const float* __restrict__ in, float* __restrict__ out) {
  __shared__ float tile[HSZ * LDSS];  // 4224 B

  const int bid = blockIdx.x;         // ((b*63 + a) * 32 + i)
  const int i  = bid & 31;
  const int ba = bid >> 5;
  const int a  = ba % 63;
  const int b  = ba / 63;
  const int p  = a + i - 31;
  const int t  = threadIdx.x;

  float* outbase = out + (size_t)(b * 3969 + a * 63) * 1024 + i * 32;

  if ((unsigned)p < 32u) {
    // ---- load 32x32 input tile: row q is 128B contiguous ----
    const float* inbase = in + (size_t)(b * 1024 + p * 32) * 1024 + i * 32;
    {
      const int q  = t >> 3;          // 0..31
      const int j0 = (t & 7) * 4;     // 0,4,...,28
      const float4 v =
          *reinterpret_cast<const float4*>(inbase + (size_t)q * 1024 + j0);
      float* row = &tile[q * LDSS + j0];
      row[0] = v.x; row[1] = v.y; row[2] = v.z; row[3] = v.w;
    }
    __syncthreads();

    // ---- emit 63 output rows (c), 8 float4 each: diagonal LDS read ----
    for (int task = t; task < HH * 8; task += 256) {
      const int c  = task >> 3;
      const int j0 = (task & 7) * 4;
      float4 v;
      float* vp = reinterpret_cast<float*>(&v);
#pragma unroll
      for (int k = 0; k < 4; ++k) {
        const int j = j0 + k;
        const int q = c + j - 31;
        vp[k] = ((unsigned)q < 32u) ? tile[q * LDSS + j] : 0.0f;
      }
      *reinterpret_cast<float4*>(outbase + (size_t)c * 1024 + j0) = v;
    }
  } else {
    // ---- p out of range: whole (c, j) plane for this (b, a, i) is zero ----
    const float4 z = make_float4(0.f, 0.f, 0.f, 0.f);
    for (int task = t; task < HH * 8; task += 256) {
      const int c  = task >> 3;
      const int j0 = (task & 7) * 4;
      *reinterpret_cast<float4*>(outbase + (size_t)c * 1024 + j0) = z;
    }
  }
}

extern "C" void kernel_launch(void* const* d_in, const int* in_sizes, int n_in,
                              void* d_out, int out_size, void* d_ws,
                              size_t ws_size, hipStream_t stream) {
  (void)in_sizes; (void)n_in; (void)out_size; (void)d_ws; (void)ws_size;
  const float* in = (const float*)d_in[0];
  float* out = (float*)d_out;
  const int grid = 16 * 63 * 32;  // one block per (b, a, i)
  CorrelationAlign_kernel<<<grid, 256, 0, stream>>>(in, out);
}